// Round 7
// baseline (256.221 us; speedup 1.0000x reference)
//
#include <hip/hip_runtime.h>

typedef unsigned int   uint32;
typedef unsigned short ushort16;

#define NN       50000
#define RR       16
#define BB       8
#define DIN      128
#define DOUT     128
#define K2       1024          // B*DIN (basis-combined K)
#define NNZ_C    1600000
#define NBUCK    196           // row>>8 buckets (256 rows each)
#define EPB      4096          // edges per block in sort passes
#define NBLK_E   391           // ceil(NNZ/EPB)
#define PREP_BST 512           // prep kernel block ranges
#define PREP_CVT 12500
#define PREP_G   (PREP_BST + PREP_CVT + NBLK_E)   // 13403

typedef short  short8  __attribute__((ext_vector_type(8)));
typedef float  floatx4 __attribute__((ext_vector_type(4)));
typedef float  float2v __attribute__((ext_vector_type(2)));

__device__ __forceinline__ ushort16 f2bf(float f) {
    uint32 u = __float_as_uint(f);
    u += 0x7fffu + ((u >> 16) & 1u);   // RNE
    return (ushort16)(u >> 16);
}

// pack two f32 -> (bf16(b)<<16)|bf16(a), round-half-up
__device__ __forceinline__ uint32 pack_bf16(float a, float b) {
    uint32 ua = __float_as_uint(a) + 0x8000u;
    uint32 ub = __float_as_uint(b) + 0x8000u;
    return __builtin_amdgcn_perm(ub, ua, 0x07060302);
}

// async global->LDS, 16B per lane; LDS dest = uniform base + lane*16
__device__ __forceinline__ void gload16(const void* g, void* l) {
    __builtin_amdgcn_global_load_lds(
        (const __attribute__((address_space(1))) uint32*)g,
        (__attribute__((address_space(3))) uint32*)l, 16, 0, 0);
}

// ---------------------------------------------------------------------------
// Prep (merged prologue): blocks [0,512) build Bst transpose-cast;
// [512,13012) convert X f32 -> packed bf16 dwords; [13012,13403) bucket
// histogram of rows. Branch is uniform per block; bodies are the proven
// round-0 kernels verbatim.
// ---------------------------------------------------------------------------
__global__ __launch_bounds__(256) void prep_kernel(
        const float* __restrict__ basis,
        const float* __restrict__ X,
        const int* __restrict__ rows,
        ushort16* __restrict__ Bst,
        uint32* __restrict__ XD,
        int* __restrict__ counts) {
    __shared__ int h[NBUCK];
    int tid = threadIdx.x;
    int bid = blockIdx.x;
    if (bid < PREP_BST) {
        // Bst[jout][b*128+jin] = basis[b][jin][jout]
        int idx  = bid * 256 + tid;
        int jout = idx >> 10;
        int bk   = idx & 1023;           // b*128 + jin
        Bst[idx] = f2bf(basis[(size_t)bk * DOUT + jout]);
    } else if (bid < PREP_BST + PREP_CVT) {
        int d = (bid - PREP_BST) * 256 + tid;
        float2 f = *(const float2*)(X + (size_t)d * 2);
        XD[d] = pack_bf16(f.x, f.y);
    } else {
        if (tid < NBUCK) h[tid] = 0;
        __syncthreads();
        int base_e = (bid - PREP_BST - PREP_CVT) * EPB;
#pragma unroll
        for (int it = 0; it < 16; ++it) {
            int e = base_e + it * 256 + tid;
            if (e < NNZ_C) atomicAdd(&h[rows[e] >> 8], 1);
        }
        __syncthreads();
        if (tid < NBUCK && h[tid]) atomicAdd(&counts[tid], h[tid]);
    }
}

// ---------------------------------------------------------------------------
// Sort pass 2: scan 196 bucket counts (single block); init cursors
// ---------------------------------------------------------------------------
__global__ void scanB_kernel(const int* __restrict__ counts,
                             int* __restrict__ bucket_start,
                             int* __restrict__ cursor) {
    __shared__ int tmp[256];
    int tid = threadIdx.x;
    int v = (tid < NBUCK) ? counts[tid] : 0;
    tmp[tid] = v;
    __syncthreads();
#pragma unroll
    for (int off = 1; off < 256; off <<= 1) {
        int t = (tid >= off) ? tmp[tid - off] : 0;
        __syncthreads();
        tmp[tid] += t;
        __syncthreads();
    }
    if (tid < NBUCK) {
        bucket_start[tid + 1] = tmp[tid];          // inclusive
        cursor[tid] = tmp[tid] - v;                // exclusive
        if (tid == 0) bucket_start[0] = 0;
    }
}

// ---------------------------------------------------------------------------
// Sort pass 3: per-block range reservation + scatter into bucket-grouped es2.
// payload x = c(16b) | kl(12b)<<16, kl = (row&255)*16 + r ; y = val bits
// ---------------------------------------------------------------------------
__global__ __launch_bounds__(256) void scatterB_kernel(
        const int* __restrict__ rows,
        const int* __restrict__ cols,
        const float* __restrict__ vals,
        int* __restrict__ cursor,
        uint2* __restrict__ es2) {
    __shared__ int h[NBUCK], gbase[NBUCK], lcur[NBUCK];
    int tid = threadIdx.x;
    if (tid < NBUCK) { h[tid] = 0; lcur[tid] = 0; }
    __syncthreads();

    int    rowv[16];
    uint32 pkx[16];
    float  vv[16];
    int base_e = blockIdx.x * EPB;
#pragma unroll
    for (int it = 0; it < 16; ++it) {
        int e = base_e + it * 256 + tid;
        if (e < NNZ_C) {
            int row = rows[e];
            int col = cols[e];
            int r   = (int)((uint32)col / (uint32)NN);
            int c   = col - r * NN;
            rowv[it] = row;
            pkx[it]  = (uint32)c | ((uint32)(((row & 255) << 4) | r) << 16);
            vv[it]   = vals[e];
            atomicAdd(&h[row >> 8], 1);
        } else rowv[it] = -1;
    }
    __syncthreads();
    if (tid < NBUCK && h[tid] > 0)
        gbase[tid] = atomicAdd(&cursor[tid], h[tid]);
    __syncthreads();
#pragma unroll
    for (int it = 0; it < 16; ++it) {
        if (rowv[it] >= 0) {
            int b   = rowv[it] >> 8;
            int pos = gbase[b] + atomicAdd(&lcur[b], 1);
            es2[pos] = make_uint2(pkx[it], __float_as_uint(vv[it]));
        }
    }
}

// ---------------------------------------------------------------------------
// Sort pass 4: one block per bucket — LDS counting-sort by sub-key
// kl = (row&255)*16 + r ; writes final es (x = c | r<<16, y = val) and
// ks[b*4096 + kl] == ks[row*16 + r] = global segment start.
// ---------------------------------------------------------------------------
__global__ __launch_bounds__(256) void sortB_kernel(
        const uint2* __restrict__ es2,
        const int* __restrict__ bucket_start,
        uint2* __restrict__ es,
        int* __restrict__ ks) {
    __shared__ int h[4096];
    __shared__ int cur[4096];
    __shared__ int tmp[256];
    int b    = blockIdx.x;
    int tid  = threadIdx.x;
    int base = bucket_start[b];
    int n    = bucket_start[b + 1] - base;

#pragma unroll
    for (int j = 0; j < 16; ++j) h[j * 256 + tid] = 0;
    __syncthreads();
    for (int i = tid; i < n; i += 256) {
        uint2 p = es2[base + i];
        atomicAdd(&h[(p.x >> 16) & 0xfffu], 1);
    }
    __syncthreads();

    // block-wide exclusive scan over 4096 counters
    int run = 0;
    int loc[16];
#pragma unroll
    for (int j = 0; j < 16; ++j) {
        int c = h[tid * 16 + j];
        loc[j] = run;
        run += c;
    }
    tmp[tid] = run;
    __syncthreads();
#pragma unroll
    for (int off = 1; off < 256; off <<= 1) {
        int t = (tid >= off) ? tmp[tid - off] : 0;
        __syncthreads();
        tmp[tid] += t;
        __syncthreads();
    }
    int excl_t = tmp[tid] - run;
#pragma unroll
    for (int j = 0; j < 16; ++j) {
        int idx = tid * 16 + j;
        int st  = loc[j] + excl_t;
        cur[idx] = st;
        ks[b * 4096 + idx] = base + st;
    }
    __syncthreads();

    for (int i = tid; i < n; i += 256) {
        uint2 p  = es2[base + i];
        int   kl = (p.x >> 16) & 0xfffu;
        int  pos = atomicAdd(&cur[kl], 1);
        // final payload keeps r (= kl&15) in bits 16..19
        es[base + pos] = make_uint2((p.x & 0xffffu) | ((uint32)(kl & 15) << 16),
                                    p.y);
    }
}

// ---------------------------------------------------------------------------
// Zc build, scalarized: one wave per row. Edge stream is (row,r)-sorted with
// r embedded in es.x[19:16]; records are wave-uniform -> readfirstlane puts
// ALL control (bounds, r-switch detection, fold triggering) on the SALU pipe.
// Per edge: 1 coalesced 256B X-row gather (scalar base + lane*4) + 1 packed
// FMA. Fold into 8 comp-weighted basis accumulators only when r changes.
// ---------------------------------------------------------------------------
__global__ __launch_bounds__(256) void zc_build_kernel(
        const uint2* __restrict__ es,
        const int* __restrict__ ks,
        const uint32* __restrict__ XD,
        const float* __restrict__ comp,
        uint32* __restrict__ ZD) {
    __shared__ __align__(16) float comp_l[128];
    int tid = threadIdx.x;
    if (tid < 128) comp_l[tid] = comp[tid];
    __syncthreads();

    const int row  = __builtin_amdgcn_readfirstlane(blockIdx.x * 4 + (tid >> 6));
    const int lane = tid & 63;

    int beg = __builtin_amdgcn_readfirstlane(ks[row * 16]);
    int end = __builtin_amdgcn_readfirstlane(ks[row * 16 + 16]); // ==NNZ for last row

    float2v zb[8];
#pragma unroll
    for (int b = 0; b < 8; ++b) zb[b] = (float2v){0.f, 0.f};

    if (beg < end) {
        const int endm1 = end - 1;
        float2v a = (float2v){0.f, 0.f};

#define LREC(C, R, V, IDX)                                                 \
        { int i_ = (IDX) < endm1 ? (IDX) : endm1;                          \
          uint2 pz_ = es[i_];                                              \
          uint32 px_ = __builtin_amdgcn_readfirstlane(pz_.x);              \
          V = __uint_as_float(__builtin_amdgcn_readfirstlane(pz_.y));      \
          C = (int)(px_ & 0xffffu); R = (int)(px_ >> 16); }

#define LX(X, C)  X = XD[((size_t)(C) << 6) + lane];

#define FOLD                                                               \
        { float4 c0_ = *(const float4*)&comp_l[r_cur * 8];                 \
          float4 c1_ = *(const float4*)&comp_l[r_cur * 8 + 4];             \
          zb[0] += c0_.x * a; zb[1] += c0_.y * a;                          \
          zb[2] += c0_.z * a; zb[3] += c0_.w * a;                          \
          zb[4] += c1_.x * a; zb[5] += c1_.y * a;                          \
          zb[6] += c1_.z * a; zb[7] += c1_.w * a; }

#define CONS(R, V, X, K)                                                   \
        if (e + (K) < end) {                                               \
            if ((R) != r_cur) {                                            \
                FOLD                                                       \
                a = (float2v){0.f, 0.f};                                   \
                r_cur = (R);                                               \
            }                                                              \
            float2v xf_;                                                   \
            xf_.x = __uint_as_float((X) << 16);                            \
            xf_.y = __uint_as_float((X) & 0xffff0000u);                    \
            a += (V) * xf_;                                                \
        }

        int   cA0, cA1, cA2, cA3, rA0, rA1, rA2, rA3;
        int   cB0, cB1, cB2, cB3, rB0, rB1, rB2, rB3;
        float vA0, vA1, vA2, vA3, vB0, vB1, vB2, vB3;
        uint32 xA0, xA1, xA2, xA3;

        LREC(cA0, rA0, vA0, beg + 0)
        LREC(cA1, rA1, vA1, beg + 1)
        LREC(cA2, rA2, vA2, beg + 2)
        LREC(cA3, rA3, vA3, beg + 3)
        LREC(cB0, rB0, vB0, beg + 4)
        LREC(cB1, rB1, vB1, beg + 5)
        LREC(cB2, rB2, vB2, beg + 6)
        LREC(cB3, rB3, vB3, beg + 7)
        LX(xA0, cA0) LX(xA1, cA1) LX(xA2, cA2) LX(xA3, cA3)

        int r_cur = rA0;

        for (int e = beg; e < end; e += 8) {
            uint32 xB0, xB1, xB2, xB3;
            LX(xB0, cB0) LX(xB1, cB1) LX(xB2, cB2) LX(xB3, cB3)
            int cC0, cC1, cC2, cC3, rC0, rC1, rC2, rC3;
            float vC0, vC1, vC2, vC3;
            LREC(cC0, rC0, vC0, e + 8)
            LREC(cC1, rC1, vC1, e + 9)
            LREC(cC2, rC2, vC2, e + 10)
            LREC(cC3, rC3, vC3, e + 11)

            CONS(rA0, vA0, xA0, 0)
            CONS(rA1, vA1, xA1, 1)
            CONS(rA2, vA2, xA2, 2)
            CONS(rA3, vA3, xA3, 3)

            uint32 xC0, xC1, xC2, xC3;
            LX(xC0, cC0) LX(xC1, cC1) LX(xC2, cC2) LX(xC3, cC3)
            int cD0, cD1, cD2, cD3, rD0, rD1, rD2, rD3;
            float vD0, vD1, vD2, vD3;
            LREC(cD0, rD0, vD0, e + 12)
            LREC(cD1, rD1, vD1, e + 13)
            LREC(cD2, rD2, vD2, e + 14)
            LREC(cD3, rD3, vD3, e + 15)

            CONS(rB0, vB0, xB0, 4)
            CONS(rB1, vB1, xB1, 5)
            CONS(rB2, vB2, xB2, 6)
            CONS(rB3, vB3, xB3, 7)

            // rotate C->A (records + x), D->B (records)
            cA0 = cC0; cA1 = cC1; cA2 = cC2; cA3 = cC3;
            rA0 = rC0; rA1 = rC1; rA2 = rC2; rA3 = rC3;
            vA0 = vC0; vA1 = vC1; vA2 = vC2; vA3 = vC3;
            xA0 = xC0; xA1 = xC1; xA2 = xC2; xA3 = xC3;
            cB0 = cD0; cB1 = cD1; cB2 = cD2; cB3 = cD3;
            rB0 = rD0; rB1 = rD1; rB2 = rD2; rB3 = rD3;
            vB0 = vD0; vB1 = vD1; vB2 = vD2; vB3 = vD3;
        }
        FOLD   // final run
#undef CONS
#undef FOLD
#undef LX
#undef LREC
    }

#pragma unroll
    for (int b = 0; b < 8; ++b)
        ZD[(size_t)row * 512 + b * 64 + lane] = pack_bf16(zb[b].x, zb[b].y);
}

// ---------------------------------------------------------------------------
// Dense GEMM (m97-style): out[n, jout] = sum_k Zc[n, k] * Bst[jout, k].
// Block = 128 rows x 128 jout, 256 thr (4 waves, 2x2), K=1024 in 16 BK=64
// slabs. A+B staged via global_load_lds(16B); fragment reads ds_read_b128
// with XOR chunk-swizzle p = row*8 + (kc ^ (row&7)) -> 2-way banks (free).
// ---------------------------------------------------------------------------
__global__ __launch_bounds__(256) void gemm_out_kernel(
        const ushort16* __restrict__ Zc,
        const ushort16* __restrict__ Bst,
        float* __restrict__ out) {
    __shared__ __align__(16) char lds[32768];
    char* Al = lds;               // 16 KB: A slab 128 rows x 64 k
    char* Bl = lds + 16384;       // 16 KB: B slab 128 jout x 64 k

    const int tid  = threadIdx.x;
    const int wave = tid >> 6;
    const int lane = tid & 63;
    const int m    = lane & 15;
    const int half = lane >> 4;
    const int wr   = wave >> 1;          // row half of block
    const int wc   = wave & 1;           // col half of block
    const size_t arow0 = (size_t)blockIdx.x * 128;

    floatx4 acc[16] = {};

    for (int slab = 0; slab < 16; ++slab) {
        const int k0 = slab * 64;
        // stage: physical chunk s holds (row = s>>3, kc = (s&7)^(row&7))
#pragma unroll
        for (int rd = 0; rd < 4; ++rd) {
            int s   = rd * 256 + wave * 64 + lane;
            int row = s >> 3;
            int kc  = (s & 7) ^ (row & 7);
            size_t ldsoff = (size_t)(rd * 256 + wave * 64) * 16;
            gload16(Zc  + ((arow0 + row) << 10) + k0 + (kc << 3), Al + ldsoff);
            gload16(Bst + ((size_t)row << 10)   + k0 + (kc << 3), Bl + ldsoff);
        }
        __syncthreads();

#pragma unroll
        for (int c = 0; c < 2; ++c) {
            short8 a[4], bfr[4];
#pragma unroll
            for (int mt = 0; mt < 4; ++mt) {
                int row = wr * 64 + mt * 16 + m;
                int p   = row * 8 + ((c * 4 + half) ^ (m & 7));
                a[mt] = *(const short8*)(Al + p * 16);
            }
#pragma unroll
            for (int nt = 0; nt < 4; ++nt) {
                int rowb = wc * 64 + nt * 16 + m;
                int p    = rowb * 8 + ((c * 4 + half) ^ (m & 7));
                bfr[nt] = *(const short8*)(Bl + p * 16);
            }
#pragma unroll
            for (int mt = 0; mt < 4; ++mt)
#pragma unroll
                for (int nt = 0; nt < 4; ++nt)
                    acc[mt * 4 + nt] = __builtin_amdgcn_mfma_f32_16x16x32_bf16(
                        a[mt], bfr[nt], acc[mt * 4 + nt], 0, 0, 0);
        }
        __syncthreads();
    }

    // epilogue: C/D layout col = m (jout tile), row = half*4 + reg
#pragma unroll
    for (int mt = 0; mt < 4; ++mt) {
#pragma unroll
        for (int reg = 0; reg < 4; ++reg) {
            int grow = (int)arow0 + wr * 64 + mt * 16 + half * 4 + reg;
            if (grow < NN) {
#pragma unroll
                for (int nt = 0; nt < 4; ++nt)
                    out[(size_t)grow * DOUT + wc * 64 + nt * 16 + m] =
                        acc[mt * 4 + nt][reg];
            }
        }
    }
}

// ---------------------------------------------------------------------------
extern "C" void kernel_launch(void* const* d_in, const int* in_sizes, int n_in,
                              void* d_out, int out_size, void* d_ws, size_t ws_size,
                              hipStream_t stream) {
    const float* X      = (const float*)d_in[0];
    const int*   A_rows = (const int*)d_in[1];
    const int*   A_cols = (const int*)d_in[2];
    const float* A_vals = (const float*)d_in[3];
    const float* basis  = (const float*)d_in[4];
    const float* comp   = (const float*)d_in[5];
    float* out = (float*)d_out;

    // workspace layout (peak ~144.6 MB, under the proven 218.7 MB budget)
    char* ws = (char*)d_ws;
    ushort16* Bst          = (ushort16*)(ws + 0);            // 256 KB
    uint32*   XD           = (uint32*)(ws + 524288);         // 12.8 MB
    int*      ks           = (int*)(ws + 13324288);          // 802816 ints
    uint2*    es           = (uint2*)(ws + 16535552);        // 12.8 MB
    int*      bucket_start = (int*)(ws + 29335552);          // 197 ints
    int*      counts       = (int*)(ws + 29336576);          // 196 ints
    int*      cursor       = (int*)(ws + 29337600);          // 196 ints
    uint2*    es2          = (uint2*)(ws + 29339648);        // 12.8 MB
    ushort16* Zc           = (ushort16*)(ws + 42139648);     // 102.4 MB
    uint32*   ZD           = (uint32*)Zc;

    hipMemsetAsync(counts, 0, NBUCK * sizeof(int), stream);

    prep_kernel<<<PREP_G, 256, 0, stream>>>(basis, X, A_rows, Bst, XD, counts);
    scanB_kernel<<<1, 256, 0, stream>>>(counts, bucket_start, cursor);
    scatterB_kernel<<<NBLK_E, 256, 0, stream>>>(A_rows, A_cols, A_vals,
                                                cursor, es2);
    sortB_kernel<<<NBUCK, 256, 0, stream>>>(es2, bucket_start, es, ks);

    zc_build_kernel<<<12500, 256, 0, stream>>>(es, ks, XD, comp, ZD);

    gemm_out_kernel<<<(NN + 127) / 128, 256, 0, stream>>>(Zc, Bst, out);
}